// Round 14
// baseline (118.864 us; speedup 1.0000x reference)
//
#include <hip/hip_runtime.h>

constexpr int Wd = 512;
constexpr int PLANE = 512 * 512;

typedef float v2f __attribute__((ext_vector_type(2)));

// Whole-wave lane shifts via gfx9 DPP.
__device__ __forceinline__ float dpp_up1(float x) {
    return __int_as_float(__builtin_amdgcn_update_dpp(
        0, __float_as_int(x), 0x138, 0xF, 0xF, true));
}
__device__ __forceinline__ float dpp_down1(float x) {
    return __int_as_float(__builtin_amdgcn_update_dpp(
        0, __float_as_int(x), 0x130, 0xF, 0xF, true));
}

// ---------------- kernel 1: per-plane-segment min/max partials ----------------
__global__ __launch_bounds__(256) void minmax_part(const float* __restrict__ pred,
                                                   const float* __restrict__ targ,
                                                   float* __restrict__ pmx,
                                                   float* __restrict__ pmn) {
    int bx = blockIdx.x;
    int plane = bx >> 3, seg = bx & 7;
    size_t base = (size_t)plane * PLANE + (size_t)seg * 32768;
    const float4* p4 = reinterpret_cast<const float4*>(pred + base);
    const float4* t4 = reinterpret_cast<const float4*>(targ + base);
    float mx = -3.0e38f, mn = 3.0e38f;
    for (int i = threadIdx.x; i < 8192; i += 256) {
        float4 a = p4[i], b = t4[i];
        mx = fmaxf(mx, fmaxf(fmaxf(fmaxf(a.x, b.x), fmaxf(a.y, b.y)),
                             fmaxf(fmaxf(a.z, b.z), fmaxf(a.w, b.w))));
        mn = fminf(mn, fminf(fminf(fminf(a.x, b.x), fminf(a.y, b.y)),
                             fminf(fminf(a.z, b.z), fminf(a.w, b.w))));
    }
    #pragma unroll
    for (int off = 32; off; off >>= 1) {
        mx = fmaxf(mx, __shfl_down(mx, off));
        mn = fminf(mn, __shfl_down(mn, off));
    }
    __shared__ float smx[4], smn[4];
    int wid = threadIdx.x >> 6, lane = threadIdx.x & 63;
    if (lane == 0) { smx[wid] = mx; smn[wid] = mn; }
    __syncthreads();
    if (threadIdx.x == 0) {
        pmx[bx] = fmaxf(fmaxf(smx[0], smx[1]), fmaxf(smx[2], smx[3]));
        pmn[bx] = fminf(fminf(smn[0], smn[1]), fminf(smn[2], smn[3]));
    }
}

// ---------------- kernel 2: finalize c1/c2 per plane (pre-scaled by 121^2) ----
__global__ void minmax_fin(const float* __restrict__ pmx, const float* __restrict__ pmn,
                           float* __restrict__ c1s, float* __restrict__ c2s, int planes) {
    int p = blockIdx.x * blockDim.x + threadIdx.x;
    if (p < planes) {
        float mx = -3.0e38f, mn = 3.0e38f;
        for (int s = 0; s < 8; ++s) {
            mx = fmaxf(mx, pmx[p * 8 + s]);
            mn = fminf(mn, pmn[p * 8 + s]);
        }
        float dr = fmaxf(mx - mn, 1e-6f);
        c1s[p] = 1.4641f * dr * dr;    // (0.01 dr)^2 * 121^2
        c2s[p] = 13.1769f * dr * dr;   // (0.03 dr)^2 * 121^2
    }
}

// ---------------- kernel 3: fused separable SSIM, 2x wave supply --------------
// 1536 blocks x 128 thr = 2 waves/block, wave owns 16 rows -> 3072 waves =
// 12 waves/CU (2x R12's supply; VGPR ~112 permits 4 waves/SIMD so HW won't
// cap). Same per-pixel structure as R12: branch-free clamped loads, 4 running
// sums {P,T,QQ,PT} packed v2f, horizontal 11-tap via prefix + DPP wave
// shifts, 1/121 folded into c1/c2/EPS. Clean TLP test: +13% loads (16-row
// init amortization) in exchange for 2x co-resident waves.
__global__ __launch_bounds__(128) void ssim_main(const float* __restrict__ pred,
                                                 const float* __restrict__ targ,
                                                 const float* __restrict__ c1s,
                                                 const float* __restrict__ c2s,
                                                 float* __restrict__ parts) {
    __shared__ float red[2];
    int bx = blockIdx.x;
    int plane = bx >> 4, tile = bx & 15;       // 16 blocks/plane
    int wid = threadIdx.x >> 6, c = threadIdx.x & 63;
    const float c1 = c1s[plane], c2 = c2s[plane];
    const v2f c1v = {c1, c1}, c2v = {c2, c2};
    const v2f k121 = {121.0f, 121.0f};
    const float* Pg = pred + (size_t)plane * PLANE;
    const float* Tg = targ + (size_t)plane * PLANE;
    int r0 = tile * 32 + wid * 16;             // first output row of this wave

    v2f vsP[4], vsT[4], vsQQ[4], vsPT[4];
    #pragma unroll
    for (int j = 0; j < 4; ++j) { vsP[j] = 0; vsT[j] = 0; vsQQ[j] = 0; vsPT[j] = 0; }

    struct RowData { float4 a0, a1, b0, b1; };

    auto load_row = [&](int r) -> RowData {
        int rc = min(max(r, 0), 511);
        const float4* prow = reinterpret_cast<const float4*>(Pg + (size_t)rc * Wd);
        const float4* trow = reinterpret_cast<const float4*>(Tg + (size_t)rc * Wd);
        RowData d;
        d.a0 = prow[2 * c]; d.a1 = prow[2 * c + 1];
        d.b0 = trow[2 * c]; d.b1 = trow[2 * c + 1];
        return d;
    };

    auto acc_w = [&](const RowData& d, float w) {
        v2f wv = {w, w};
        v2f pa[4] = {{d.a0.x, d.a0.y}, {d.a0.z, d.a0.w}, {d.a1.x, d.a1.y}, {d.a1.z, d.a1.w}};
        v2f tb[4] = {{d.b0.x, d.b0.y}, {d.b0.z, d.b0.w}, {d.b1.x, d.b1.y}, {d.b1.z, d.b1.w}};
        #pragma unroll
        for (int j = 0; j < 4; ++j) {
            vsP[j] += wv * pa[j];
            vsT[j] += wv * tb[j];
            v2f q = pa[j] * pa[j] + tb[j] * tb[j];
            vsQQ[j] += wv * q;
            v2f pt = pa[j] * tb[j];
            vsPT[j] += wv * pt;
        }
    };

    auto hsum = [&](const v2f v[4], v2f H[4]) {
        float P0 = v[0].x;
        float P1 = P0 + v[0].y;
        float P2 = P1 + v[1].x;
        float P3 = P2 + v[1].y;
        float P4 = P3 + v[2].x;
        float P5 = P4 + v[2].y;
        float P6 = P5 + v[3].x;
        float T  = P6 + v[3].y;
        float Tm  = dpp_up1(T);
        float Pm2 = dpp_up1(P2);
        float Pm3 = dpp_up1(P3);
        float Pm4 = dpp_up1(P4);
        float Pm5 = dpp_up1(P5);
        float Pm6 = dpp_up1(P6);
        float Pp0 = dpp_down1(P0);
        float Pp1 = dpp_down1(P1);
        float Pp2 = dpp_down1(P2);
        float Pp3 = dpp_down1(P3);
        float Pp4 = dpp_down1(P4);
        H[0].x = (Tm - Pm2) + P5;
        H[0].y = (Tm - Pm3) + P6;
        H[1].x = (Tm - Pm4) + T;
        H[1].y = (Tm - Pm5) + (T + Pp0);
        H[2].x = (Tm - Pm6) + (T + Pp1);
        H[2].y = T + Pp2;
        H[3].x = (T - P0) + Pp3;
        H[3].y = (T - P1) + Pp4;
    };

    v2f lsum2 = {0.0f, 0.0f};

    auto valid = [&](int r) -> float { return ((unsigned)r < 512u) ? 1.0f : 0.0f; };

    auto body = [&](int it, const RowData& E, const RowData& Lv, RowData& En, RowData& Ln) {
        En = load_row(r0 + it + 6);
        Ln = load_row(r0 + it - 4);

        acc_w(E, valid(r0 + it + 5));

        v2f H[4][4];
        hsum(vsP,  H[0]);
        hsum(vsT,  H[1]);
        hsum(vsQQ, H[2]);
        hsum(vsPT, H[3]);

        #pragma unroll
        for (int j = 0; j < 4; ++j) {
            v2f A = H[0][j], B = H[1][j];
            v2f AB = A * B, A2 = A * A, B2 = B * B;
            v2f t4 = k121 * H[3][j] - AB;
            v2f num = (2.0f * AB + c1v) * (2.0f * t4 + c2v);
            v2f ss = k121 * H[2][j] - A2 - B2;
            ss.x = fmaxf(ss.x, 0.0f); ss.y = fmaxf(ss.y, 0.0f);
            v2f den = (A2 + B2 + c1v) * (ss + c2v);
            float s0 = __fdividef(num.x, den.x + 214.358881f);  // EPS * 121^4
            float s1 = __fdividef(num.y, den.y + 214.358881f);
            v2f loss = {fmaxf((1.0f - s0) * 0.5f, 0.0f),
                        fmaxf((1.0f - s1) * 0.5f, 0.0f)};
            lsum2 += loss;
        }
        acc_w(Lv, -valid(r0 + it - 5));
    };

    // init vertical window rows r0-5 .. r0+4, two 5-row bursts (weighted)
    {
        RowData D0 = load_row(r0 - 5), D1 = load_row(r0 - 4), D2 = load_row(r0 - 3),
                D3 = load_row(r0 - 2), D4 = load_row(r0 - 1);
        acc_w(D0, valid(r0 - 5)); acc_w(D1, valid(r0 - 4)); acc_w(D2, valid(r0 - 3));
        acc_w(D3, valid(r0 - 2)); acc_w(D4, valid(r0 - 1));
        RowData D5 = load_row(r0 + 0), D6 = load_row(r0 + 1), D7 = load_row(r0 + 2),
                D8 = load_row(r0 + 3), D9 = load_row(r0 + 4);
        acc_w(D5, 1.0f); acc_w(D6, 1.0f); acc_w(D7, 1.0f);
        acc_w(D8, 1.0f); acc_w(D9, 1.0f);
    }

    RowData E0 = load_row(r0 + 5);
    RowData L0 = load_row(r0 - 5);
    RowData E1, L1;

    #pragma unroll 1
    for (int it = 0; it < 16; it += 2) {
        body(it,     E0, L0, E1, L1);
        body(it + 1, E1, L1, E0, L0);
    }

    float lsum = lsum2.x + lsum2.y;
    #pragma unroll
    for (int off = 32; off; off >>= 1) lsum += __shfl_down(lsum, off);
    if (c == 0) red[wid] = lsum;
    __syncthreads();
    if (threadIdx.x == 0) parts[bx] = red[0] + red[1];
}

// ---------------- kernel 4: deterministic final reduce ----------------
__global__ void finish(const float* __restrict__ parts, float* __restrict__ out,
                       int n, float invN) {
    float s = 0.0f;
    for (int i = threadIdx.x; i < n; i += 256) s += parts[i];
    #pragma unroll
    for (int off = 32; off; off >>= 1) s += __shfl_down(s, off);
    __shared__ float sw[4];
    int wid = threadIdx.x >> 6, lane = threadIdx.x & 63;
    if (lane == 0) sw[wid] = s;
    __syncthreads();
    if (threadIdx.x == 0) out[0] = ((sw[0] + sw[1]) + (sw[2] + sw[3])) * invN;
}

extern "C" void kernel_launch(void* const* d_in, const int* in_sizes, int n_in,
                              void* d_out, int out_size, void* d_ws, size_t ws_size,
                              hipStream_t stream) {
    const float* pred = (const float*)d_in[0];
    const float* targ = (const float*)d_in[1];
    float* out = (float*)d_out;
    int planes = in_sizes[0] / PLANE;  // 96
    int Gm = planes * 8;               // 768 blocks for minmax
    int Gs = planes * 16;              // 1536 blocks for ssim

    float* ws   = (float*)d_ws;
    float* pmx  = ws;                   // Gm
    float* pmn  = ws + Gm;              // Gm
    float* c1s  = ws + 2 * Gm;          // planes
    float* c2s  = ws + 2 * Gm + planes; // planes
    float* prts = ws + 2 * Gm + 2 * planes;  // Gs

    minmax_part<<<Gm, 256, 0, stream>>>(pred, targ, pmx, pmn);
    minmax_fin<<<(planes + 127) / 128, 128, 0, stream>>>(pmx, pmn, c1s, c2s, planes);
    ssim_main<<<Gs, 128, 0, stream>>>(pred, targ, c1s, c2s, prts);
    float invN = 1.0f / ((float)planes * (float)PLANE);
    finish<<<1, 256, 0, stream>>>(prts, out, Gs, invN);
}

// Round 15
// 113.930 us; speedup vs baseline: 1.0433x; 1.0433x over previous
//
#include <hip/hip_runtime.h>

constexpr int Wd = 512;
constexpr int PLANE = 512 * 512;

typedef float v2f __attribute__((ext_vector_type(2)));

// Whole-wave lane shifts via gfx9 DPP.
__device__ __forceinline__ float dpp_up1(float x) {
    return __int_as_float(__builtin_amdgcn_update_dpp(
        0, __float_as_int(x), 0x138, 0xF, 0xF, true));
}
__device__ __forceinline__ float dpp_down1(float x) {
    return __int_as_float(__builtin_amdgcn_update_dpp(
        0, __float_as_int(x), 0x130, 0xF, 0xF, true));
}

// ---------------- kernel 1: per-plane-segment min/max partials ----------------
__global__ __launch_bounds__(256) void minmax_part(const float* __restrict__ pred,
                                                   const float* __restrict__ targ,
                                                   float* __restrict__ pmx,
                                                   float* __restrict__ pmn) {
    int bx = blockIdx.x;
    int plane = bx >> 3, seg = bx & 7;
    size_t base = (size_t)plane * PLANE + (size_t)seg * 32768;
    const float4* p4 = reinterpret_cast<const float4*>(pred + base);
    const float4* t4 = reinterpret_cast<const float4*>(targ + base);
    float mx = -3.0e38f, mn = 3.0e38f;
    for (int i = threadIdx.x; i < 8192; i += 256) {
        float4 a = p4[i], b = t4[i];
        mx = fmaxf(mx, fmaxf(fmaxf(fmaxf(a.x, b.x), fmaxf(a.y, b.y)),
                             fmaxf(fmaxf(a.z, b.z), fmaxf(a.w, b.w))));
        mn = fminf(mn, fminf(fminf(fminf(a.x, b.x), fminf(a.y, b.y)),
                             fminf(fminf(a.z, b.z), fminf(a.w, b.w))));
    }
    #pragma unroll
    for (int off = 32; off; off >>= 1) {
        mx = fmaxf(mx, __shfl_down(mx, off));
        mn = fminf(mn, __shfl_down(mn, off));
    }
    __shared__ float smx[4], smn[4];
    int wid = threadIdx.x >> 6, lane = threadIdx.x & 63;
    if (lane == 0) { smx[wid] = mx; smn[wid] = mn; }
    __syncthreads();
    if (threadIdx.x == 0) {
        pmx[bx] = fmaxf(fmaxf(smx[0], smx[1]), fmaxf(smx[2], smx[3]));
        pmn[bx] = fminf(fminf(smn[0], smn[1]), fminf(smn[2], smn[3]));
    }
}

// ---------------- kernel 2: finalize c1/c2 per plane (pre-scaled by 121^2) ----
__global__ void minmax_fin(const float* __restrict__ pmx, const float* __restrict__ pmn,
                           float* __restrict__ c1s, float* __restrict__ c2s, int planes) {
    int p = blockIdx.x * blockDim.x + threadIdx.x;
    if (p < planes) {
        float mx = -3.0e38f, mn = 3.0e38f;
        for (int s = 0; s < 8; ++s) {
            mx = fmaxf(mx, pmx[p * 8 + s]);
            mn = fminf(mn, pmn[p * 8 + s]);
        }
        float dr = fmaxf(mx - mn, 1e-6f);
        c1s[p] = 1.4641f * dr * dr;    // (0.01 dr)^2 * 121^2
        c2s[p] = 13.1769f * dr * dr;   // (0.03 dr)^2 * 121^2
    }
}

// ---------------- kernel 3: fused separable SSIM, wave-peeled fast path -------
// 768 blocks x 128 thr = 2 waves/block; wave owns 32 rows, lane owns 8 cols.
// Waves whose 32-row strip never touches a plane boundary (r0 in [6,474]:
// 14 of every 16) take a FAST path: no clamps, no validity weights, plain
// add/sub running-sum updates, monotonic row offsets. Boundary waves take the
// generic weighted path. Four running sums {P,T,QQ,PT} packed v2f; horizontal
// 11-tap via prefix + DPP wave shifts; 1/121 folded into c1/c2/EPS; 0.5 loss
// scale hoisted out of the pixel loop.
__global__ __launch_bounds__(128) void ssim_main(const float* __restrict__ pred,
                                                 const float* __restrict__ targ,
                                                 const float* __restrict__ c1s,
                                                 const float* __restrict__ c2s,
                                                 float* __restrict__ parts) {
    __shared__ float red[2];
    int bx = blockIdx.x;
    int plane = bx >> 3, tile = bx & 7;
    int wid = threadIdx.x >> 6, c = threadIdx.x & 63;
    const float c1 = c1s[plane], c2 = c2s[plane];
    const v2f c1v = {c1, c1}, c2v = {c2, c2};
    const v2f k121 = {121.0f, 121.0f};
    const float* Pg = pred + (size_t)plane * PLANE;
    const float* Tg = targ + (size_t)plane * PLANE;
    int r0 = tile * 64 + wid * 32;

    v2f vsP[4], vsT[4], vsQQ[4], vsPT[4];
    #pragma unroll
    for (int j = 0; j < 4; ++j) { vsP[j] = 0; vsT[j] = 0; vsQQ[j] = 0; vsPT[j] = 0; }

    struct RowData { float4 a0, a1, b0, b1; };

    // load at a raw row offset (row guaranteed in-bounds)
    auto load_at = [&](size_t rowOff) -> RowData {
        const float4* prow = reinterpret_cast<const float4*>(Pg + rowOff);
        const float4* trow = reinterpret_cast<const float4*>(Tg + rowOff);
        RowData d;
        d.a0 = prow[2 * c]; d.a1 = prow[2 * c + 1];
        d.b0 = trow[2 * c]; d.b1 = trow[2 * c + 1];
        return d;
    };
    // clamped load (generic path)
    auto load_row = [&](int r) -> RowData {
        int rc = min(max(r, 0), 511);
        return load_at((size_t)rc * Wd);
    };

    auto unpack = [&](const RowData& d, v2f pa[4], v2f tb[4]) {
        pa[0] = {d.a0.x, d.a0.y}; pa[1] = {d.a0.z, d.a0.w};
        pa[2] = {d.a1.x, d.a1.y}; pa[3] = {d.a1.z, d.a1.w};
        tb[0] = {d.b0.x, d.b0.y}; tb[1] = {d.b0.z, d.b0.w};
        tb[2] = {d.b1.x, d.b1.y}; tb[3] = {d.b1.z, d.b1.w};
    };

    auto acc_add = [&](const RowData& d) {
        v2f pa[4], tb[4]; unpack(d, pa, tb);
        #pragma unroll
        for (int j = 0; j < 4; ++j) {
            vsP[j] += pa[j];
            vsT[j] += tb[j];
            vsQQ[j] += pa[j] * pa[j] + tb[j] * tb[j];
            vsPT[j] += pa[j] * tb[j];
        }
    };
    auto acc_sub = [&](const RowData& d) {
        v2f pa[4], tb[4]; unpack(d, pa, tb);
        #pragma unroll
        for (int j = 0; j < 4; ++j) {
            vsP[j] -= pa[j];
            vsT[j] -= tb[j];
            vsQQ[j] -= pa[j] * pa[j] + tb[j] * tb[j];
            vsPT[j] -= pa[j] * tb[j];
        }
    };
    auto acc_w = [&](const RowData& d, float w) {
        v2f wv = {w, w};
        v2f pa[4], tb[4]; unpack(d, pa, tb);
        #pragma unroll
        for (int j = 0; j < 4; ++j) {
            vsP[j] += wv * pa[j];
            vsT[j] += wv * tb[j];
            v2f q = pa[j] * pa[j] + tb[j] * tb[j];
            vsQQ[j] += wv * q;
            v2f pt = pa[j] * tb[j];
            vsPT[j] += wv * pt;
        }
    };

    auto hsum = [&](const v2f v[4], v2f H[4]) {
        float P0 = v[0].x;
        float P1 = P0 + v[0].y;
        float P2 = P1 + v[1].x;
        float P3 = P2 + v[1].y;
        float P4 = P3 + v[2].x;
        float P5 = P4 + v[2].y;
        float P6 = P5 + v[3].x;
        float T  = P6 + v[3].y;
        float Tm  = dpp_up1(T);
        float Pm2 = dpp_up1(P2);
        float Pm3 = dpp_up1(P3);
        float Pm4 = dpp_up1(P4);
        float Pm5 = dpp_up1(P5);
        float Pm6 = dpp_up1(P6);
        float Pp0 = dpp_down1(P0);
        float Pp1 = dpp_down1(P1);
        float Pp2 = dpp_down1(P2);
        float Pp3 = dpp_down1(P3);
        float Pp4 = dpp_down1(P4);
        H[0].x = (Tm - Pm2) + P5;
        H[0].y = (Tm - Pm3) + P6;
        H[1].x = (Tm - Pm4) + T;
        H[1].y = (Tm - Pm5) + (T + Pp0);
        H[2].x = (Tm - Pm6) + (T + Pp1);
        H[2].y = T + Pp2;
        H[3].x = (T - P0) + Pp3;
        H[3].y = (T - P1) + Pp4;
    };

    v2f lsum2 = {0.0f, 0.0f};

    // shared epilogue: accumulates max(1-ssim, 0) (0.5 scale hoisted)
    auto epilogue = [&]() {
        v2f H[4][4];
        hsum(vsP,  H[0]);
        hsum(vsT,  H[1]);
        hsum(vsQQ, H[2]);
        hsum(vsPT, H[3]);
        #pragma unroll
        for (int j = 0; j < 4; ++j) {
            v2f A = H[0][j], B = H[1][j];
            v2f AB = A * B, A2 = A * A, B2 = B * B;
            v2f t4 = k121 * H[3][j] - AB;
            v2f num = (2.0f * AB + c1v) * (2.0f * t4 + c2v);
            v2f ss = k121 * H[2][j] - A2 - B2;
            ss.x = fmaxf(ss.x, 0.0f); ss.y = fmaxf(ss.y, 0.0f);
            v2f den = (A2 + B2 + c1v) * (ss + c2v);
            float s0 = __fdividef(num.x, den.x + 214.358881f);  // EPS * 121^4
            float s1 = __fdividef(num.y, den.y + 214.358881f);
            lsum2.x += fmaxf(1.0f - s0, 0.0f);
            lsum2.y += fmaxf(1.0f - s1, 0.0f);
        }
    };

    const bool fastwave = (r0 >= 6) && (r0 + 37 <= 511);

    if (fastwave) {
        // ---- fast path: no clamps, no weights ----
        {
            size_t off = (size_t)(r0 - 5) * Wd;
            RowData D0 = load_at(off + 0 * Wd), D1 = load_at(off + 1 * Wd),
                    D2 = load_at(off + 2 * Wd), D3 = load_at(off + 3 * Wd),
                    D4 = load_at(off + 4 * Wd);
            acc_add(D0); acc_add(D1); acc_add(D2); acc_add(D3); acc_add(D4);
            RowData D5 = load_at(off + 5 * Wd), D6 = load_at(off + 6 * Wd),
                    D7 = load_at(off + 7 * Wd), D8 = load_at(off + 8 * Wd),
                    D9 = load_at(off + 9 * Wd);
            acc_add(D5); acc_add(D6); acc_add(D7); acc_add(D8); acc_add(D9);
        }
        size_t eOff = (size_t)(r0 + 6) * Wd;   // next enter row to prefetch
        size_t lOff = (size_t)(r0 - 4) * Wd;   // next leave row to prefetch
        RowData E0 = load_at((size_t)(r0 + 5) * Wd);
        RowData L0 = load_at((size_t)(r0 - 5) * Wd);
        RowData E1, L1;

        auto fbody = [&](const RowData& E, const RowData& Lv, RowData& En, RowData& Ln) {
            En = load_at(eOff); eOff += Wd;
            Ln = load_at(lOff); lOff += Wd;
            acc_add(E);
            epilogue();
            acc_sub(Lv);
        };

        #pragma unroll 1
        for (int it = 0; it < 32; it += 2) {
            fbody(E0, L0, E1, L1);
            fbody(E1, L1, E0, L0);
        }
    } else {
        // ---- generic path (boundary waves) ----
        auto valid = [&](int r) -> float { return ((unsigned)r < 512u) ? 1.0f : 0.0f; };
        {
            RowData D0 = load_row(r0 - 5), D1 = load_row(r0 - 4), D2 = load_row(r0 - 3),
                    D3 = load_row(r0 - 2), D4 = load_row(r0 - 1);
            acc_w(D0, valid(r0 - 5)); acc_w(D1, valid(r0 - 4)); acc_w(D2, valid(r0 - 3));
            acc_w(D3, valid(r0 - 2)); acc_w(D4, valid(r0 - 1));
            RowData D5 = load_row(r0 + 0), D6 = load_row(r0 + 1), D7 = load_row(r0 + 2),
                    D8 = load_row(r0 + 3), D9 = load_row(r0 + 4);
            acc_w(D5, 1.0f); acc_w(D6, 1.0f); acc_w(D7, 1.0f);
            acc_w(D8, 1.0f); acc_w(D9, 1.0f);
        }
        RowData E0 = load_row(r0 + 5);
        RowData L0 = load_row(r0 - 5);
        RowData E1, L1;

        auto gbody = [&](int it, const RowData& E, const RowData& Lv, RowData& En, RowData& Ln) {
            En = load_row(r0 + it + 6);
            Ln = load_row(r0 + it - 4);
            acc_w(E, valid(r0 + it + 5));
            epilogue();
            acc_w(Lv, -valid(r0 + it - 5));
        };

        #pragma unroll 1
        for (int it = 0; it < 32; it += 2) {
            gbody(it,     E0, L0, E1, L1);
            gbody(it + 1, E1, L1, E0, L0);
        }
    }

    float lsum = lsum2.x + lsum2.y;
    #pragma unroll
    for (int off = 32; off; off >>= 1) lsum += __shfl_down(lsum, off);
    if (c == 0) red[wid] = lsum;
    __syncthreads();
    if (threadIdx.x == 0) parts[bx] = 0.5f * (red[0] + red[1]);
}

// ---------------- kernel 4: deterministic final reduce ----------------
__global__ void finish(const float* __restrict__ parts, float* __restrict__ out,
                       int n, float invN) {
    float s = 0.0f;
    for (int i = threadIdx.x; i < n; i += 256) s += parts[i];
    #pragma unroll
    for (int off = 32; off; off >>= 1) s += __shfl_down(s, off);
    __shared__ float sw[4];
    int wid = threadIdx.x >> 6, lane = threadIdx.x & 63;
    if (lane == 0) sw[wid] = s;
    __syncthreads();
    if (threadIdx.x == 0) out[0] = ((sw[0] + sw[1]) + (sw[2] + sw[3])) * invN;
}

extern "C" void kernel_launch(void* const* d_in, const int* in_sizes, int n_in,
                              void* d_out, int out_size, void* d_ws, size_t ws_size,
                              hipStream_t stream) {
    const float* pred = (const float*)d_in[0];
    const float* targ = (const float*)d_in[1];
    float* out = (float*)d_out;
    int planes = in_sizes[0] / PLANE;  // 96
    int G = planes * 8;                // 768 blocks

    float* ws   = (float*)d_ws;
    float* pmx  = ws;                  // G
    float* pmn  = ws + G;              // G
    float* c1s  = ws + 2 * G;          // planes
    float* c2s  = ws + 2 * G + planes; // planes
    float* prts = ws + 2 * G + 2 * planes;  // G

    minmax_part<<<G, 256, 0, stream>>>(pred, targ, pmx, pmn);
    minmax_fin<<<(planes + 127) / 128, 128, 0, stream>>>(pmx, pmn, c1s, c2s, planes);
    ssim_main<<<G, 128, 0, stream>>>(pred, targ, c1s, c2s, prts);
    float invN = 1.0f / ((float)planes * (float)PLANE);
    finish<<<1, 256, 0, stream>>>(prts, out, G, invN);
}

// Round 16
// 104.811 us; speedup vs baseline: 1.1341x; 1.0870x over previous
//
#include <hip/hip_runtime.h>

constexpr int Wd = 512;
constexpr int PLANE = 512 * 512;

typedef float v2f __attribute__((ext_vector_type(2)));

// Whole-wave lane shifts via gfx9 DPP.
__device__ __forceinline__ float dpp_up1(float x) {
    return __int_as_float(__builtin_amdgcn_update_dpp(
        0, __float_as_int(x), 0x138, 0xF, 0xF, true));
}
__device__ __forceinline__ float dpp_down1(float x) {
    return __int_as_float(__builtin_amdgcn_update_dpp(
        0, __float_as_int(x), 0x130, 0xF, 0xF, true));
}

// ---------------- kernel 1: per-plane-segment min/max partials ----------------
// 1536 blocks = 16 segs/plane (2x R12's parallelism: 6 blocks/CU, 24 waves/CU)
// to deepen outstanding-load supply for L3-resident streaming.
__global__ __launch_bounds__(256) void minmax_part(const float* __restrict__ pred,
                                                   const float* __restrict__ targ,
                                                   float* __restrict__ pmx,
                                                   float* __restrict__ pmn) {
    int bx = blockIdx.x;
    int plane = bx >> 4, seg = bx & 15;
    size_t base = (size_t)plane * PLANE + (size_t)seg * 16384;
    const float4* p4 = reinterpret_cast<const float4*>(pred + base);
    const float4* t4 = reinterpret_cast<const float4*>(targ + base);
    float mx = -3.0e38f, mn = 3.0e38f;
    #pragma unroll 4
    for (int i = threadIdx.x; i < 4096; i += 256) {
        float4 a = p4[i], b = t4[i];
        mx = fmaxf(mx, fmaxf(fmaxf(fmaxf(a.x, b.x), fmaxf(a.y, b.y)),
                             fmaxf(fmaxf(a.z, b.z), fmaxf(a.w, b.w))));
        mn = fminf(mn, fminf(fminf(fminf(a.x, b.x), fminf(a.y, b.y)),
                             fminf(fminf(a.z, b.z), fminf(a.w, b.w))));
    }
    #pragma unroll
    for (int off = 32; off; off >>= 1) {
        mx = fmaxf(mx, __shfl_down(mx, off));
        mn = fminf(mn, __shfl_down(mn, off));
    }
    __shared__ float smx[4], smn[4];
    int wid = threadIdx.x >> 6, lane = threadIdx.x & 63;
    if (lane == 0) { smx[wid] = mx; smn[wid] = mn; }
    __syncthreads();
    if (threadIdx.x == 0) {
        pmx[bx] = fmaxf(fmaxf(smx[0], smx[1]), fmaxf(smx[2], smx[3]));
        pmn[bx] = fminf(fminf(smn[0], smn[1]), fminf(smn[2], smn[3]));
    }
}

// ---------------- kernel 2: fused separable SSIM (R12 structure) --------------
// 768 blocks x 128 thr = 2 waves/block; wave owns 32 rows, lane owns 8 cols.
// Branch-free clamped loads; 4 running sums {P,T,QQ=PP+TT,PT} packed v2f;
// horizontal 11-tap via prefix + DPP wave shifts; 1/121 folded into c1/c2/EPS.
// c1/c2 derived inline from the 16 minmax partials (uniform scalar loads) —
// the separate minmax_fin launch is folded in here.
__global__ __launch_bounds__(128) void ssim_main(const float* __restrict__ pred,
                                                 const float* __restrict__ targ,
                                                 const float* __restrict__ pmx,
                                                 const float* __restrict__ pmn,
                                                 float* __restrict__ parts) {
    __shared__ float red[2];
    int bx = blockIdx.x;
    int plane = bx >> 3, tile = bx & 7;
    int wid = threadIdx.x >> 6, c = threadIdx.x & 63;

    // inline c1/c2 from partials (wave-uniform scalar work)
    float mx = -3.0e38f, mn = 3.0e38f;
    #pragma unroll
    for (int s = 0; s < 16; ++s) {
        mx = fmaxf(mx, pmx[plane * 16 + s]);
        mn = fminf(mn, pmn[plane * 16 + s]);
    }
    float dr = fmaxf(mx - mn, 1e-6f);
    const float c1 = 1.4641f * dr * dr;     // (0.01 dr)^2 * 121^2
    const float c2 = 13.1769f * dr * dr;    // (0.03 dr)^2 * 121^2
    const v2f c1v = {c1, c1}, c2v = {c2, c2};
    const v2f k121 = {121.0f, 121.0f};

    const float* Pg = pred + (size_t)plane * PLANE;
    const float* Tg = targ + (size_t)plane * PLANE;
    int r0 = tile * 64 + wid * 32;

    v2f vsP[4], vsT[4], vsQQ[4], vsPT[4];
    #pragma unroll
    for (int j = 0; j < 4; ++j) { vsP[j] = 0; vsT[j] = 0; vsQQ[j] = 0; vsPT[j] = 0; }

    struct RowData { float4 a0, a1, b0, b1; };

    auto load_row = [&](int r) -> RowData {
        int rc = min(max(r, 0), 511);
        const float4* prow = reinterpret_cast<const float4*>(Pg + (size_t)rc * Wd);
        const float4* trow = reinterpret_cast<const float4*>(Tg + (size_t)rc * Wd);
        RowData d;
        d.a0 = prow[2 * c]; d.a1 = prow[2 * c + 1];
        d.b0 = trow[2 * c]; d.b1 = trow[2 * c + 1];
        return d;
    };

    auto acc_w = [&](const RowData& d, float w) {
        v2f wv = {w, w};
        v2f pa[4] = {{d.a0.x, d.a0.y}, {d.a0.z, d.a0.w}, {d.a1.x, d.a1.y}, {d.a1.z, d.a1.w}};
        v2f tb[4] = {{d.b0.x, d.b0.y}, {d.b0.z, d.b0.w}, {d.b1.x, d.b1.y}, {d.b1.z, d.b1.w}};
        #pragma unroll
        for (int j = 0; j < 4; ++j) {
            vsP[j] += wv * pa[j];
            vsT[j] += wv * tb[j];
            v2f q = pa[j] * pa[j] + tb[j] * tb[j];
            vsQQ[j] += wv * q;
            v2f pt = pa[j] * tb[j];
            vsPT[j] += wv * pt;
        }
    };

    auto hsum = [&](const v2f v[4], v2f H[4]) {
        float P0 = v[0].x;
        float P1 = P0 + v[0].y;
        float P2 = P1 + v[1].x;
        float P3 = P2 + v[1].y;
        float P4 = P3 + v[2].x;
        float P5 = P4 + v[2].y;
        float P6 = P5 + v[3].x;
        float T  = P6 + v[3].y;
        float Tm  = dpp_up1(T);
        float Pm2 = dpp_up1(P2);
        float Pm3 = dpp_up1(P3);
        float Pm4 = dpp_up1(P4);
        float Pm5 = dpp_up1(P5);
        float Pm6 = dpp_up1(P6);
        float Pp0 = dpp_down1(P0);
        float Pp1 = dpp_down1(P1);
        float Pp2 = dpp_down1(P2);
        float Pp3 = dpp_down1(P3);
        float Pp4 = dpp_down1(P4);
        H[0].x = (Tm - Pm2) + P5;
        H[0].y = (Tm - Pm3) + P6;
        H[1].x = (Tm - Pm4) + T;
        H[1].y = (Tm - Pm5) + (T + Pp0);
        H[2].x = (Tm - Pm6) + (T + Pp1);
        H[2].y = T + Pp2;
        H[3].x = (T - P0) + Pp3;
        H[3].y = (T - P1) + Pp4;
    };

    v2f lsum2 = {0.0f, 0.0f};

    auto valid = [&](int r) -> float { return ((unsigned)r < 512u) ? 1.0f : 0.0f; };

    auto body = [&](int it, const RowData& E, const RowData& Lv, RowData& En, RowData& Ln) {
        En = load_row(r0 + it + 6);
        Ln = load_row(r0 + it - 4);

        acc_w(E, valid(r0 + it + 5));

        v2f H[4][4];
        hsum(vsP,  H[0]);
        hsum(vsT,  H[1]);
        hsum(vsQQ, H[2]);
        hsum(vsPT, H[3]);

        #pragma unroll
        for (int j = 0; j < 4; ++j) {
            v2f A = H[0][j], B = H[1][j];
            v2f AB = A * B, A2 = A * A, B2 = B * B;
            v2f t4 = k121 * H[3][j] - AB;
            v2f num = (2.0f * AB + c1v) * (2.0f * t4 + c2v);
            v2f ss = k121 * H[2][j] - A2 - B2;
            ss.x = fmaxf(ss.x, 0.0f); ss.y = fmaxf(ss.y, 0.0f);
            v2f den = (A2 + B2 + c1v) * (ss + c2v);
            float s0 = __fdividef(num.x, den.x + 214.358881f);  // EPS * 121^4
            float s1 = __fdividef(num.y, den.y + 214.358881f);
            v2f loss = {fmaxf((1.0f - s0) * 0.5f, 0.0f),
                        fmaxf((1.0f - s1) * 0.5f, 0.0f)};
            lsum2 += loss;
        }
        acc_w(Lv, -valid(r0 + it - 5));
    };

    // init vertical window rows r0-5 .. r0+4, two 5-row bursts (weighted)
    {
        RowData D0 = load_row(r0 - 5), D1 = load_row(r0 - 4), D2 = load_row(r0 - 3),
                D3 = load_row(r0 - 2), D4 = load_row(r0 - 1);
        acc_w(D0, valid(r0 - 5)); acc_w(D1, valid(r0 - 4)); acc_w(D2, valid(r0 - 3));
        acc_w(D3, valid(r0 - 2)); acc_w(D4, valid(r0 - 1));
        RowData D5 = load_row(r0 + 0), D6 = load_row(r0 + 1), D7 = load_row(r0 + 2),
                D8 = load_row(r0 + 3), D9 = load_row(r0 + 4);
        acc_w(D5, 1.0f); acc_w(D6, 1.0f); acc_w(D7, 1.0f);
        acc_w(D8, 1.0f); acc_w(D9, 1.0f);
    }

    RowData E0 = load_row(r0 + 5);
    RowData L0 = load_row(r0 - 5);
    RowData E1, L1;

    #pragma unroll 1
    for (int it = 0; it < 32; it += 2) {
        body(it,     E0, L0, E1, L1);
        body(it + 1, E1, L1, E0, L0);
    }

    float lsum = lsum2.x + lsum2.y;
    #pragma unroll
    for (int off = 32; off; off >>= 1) lsum += __shfl_down(lsum, off);
    if (c == 0) red[wid] = lsum;
    __syncthreads();
    if (threadIdx.x == 0) parts[bx] = red[0] + red[1];
}

// ---------------- kernel 3: deterministic final reduce ----------------
__global__ void finish(const float* __restrict__ parts, float* __restrict__ out,
                       int n, float invN) {
    float s = 0.0f;
    for (int i = threadIdx.x; i < n; i += 256) s += parts[i];
    #pragma unroll
    for (int off = 32; off; off >>= 1) s += __shfl_down(s, off);
    __shared__ float sw[4];
    int wid = threadIdx.x >> 6, lane = threadIdx.x & 63;
    if (lane == 0) sw[wid] = s;
    __syncthreads();
    if (threadIdx.x == 0) out[0] = ((sw[0] + sw[1]) + (sw[2] + sw[3])) * invN;
}

extern "C" void kernel_launch(void* const* d_in, const int* in_sizes, int n_in,
                              void* d_out, int out_size, void* d_ws, size_t ws_size,
                              hipStream_t stream) {
    const float* pred = (const float*)d_in[0];
    const float* targ = (const float*)d_in[1];
    float* out = (float*)d_out;
    int planes = in_sizes[0] / PLANE;  // 96
    int Gm = planes * 16;              // 1536 blocks for minmax
    int Gs = planes * 8;               // 768 blocks for ssim

    float* ws   = (float*)d_ws;
    float* pmx  = ws;                  // Gm
    float* pmn  = ws + Gm;             // Gm
    float* prts = ws + 2 * Gm;         // Gs

    minmax_part<<<Gm, 256, 0, stream>>>(pred, targ, pmx, pmn);
    ssim_main<<<Gs, 128, 0, stream>>>(pred, targ, pmx, pmn, prts);
    float invN = 1.0f / ((float)planes * (float)PLANE);
    finish<<<1, 256, 0, stream>>>(prts, out, Gs, invN);
}

// Round 17
// 101.094 us; speedup vs baseline: 1.1758x; 1.0368x over previous
//
#include <hip/hip_runtime.h>

constexpr int Wd = 512;
constexpr int PLANE = 512 * 512;

typedef float v2f __attribute__((ext_vector_type(2)));

// Whole-wave lane shifts via gfx9 DPP.
__device__ __forceinline__ float dpp_up1(float x) {
    return __int_as_float(__builtin_amdgcn_update_dpp(
        0, __float_as_int(x), 0x138, 0xF, 0xF, true));
}
__device__ __forceinline__ float dpp_down1(float x) {
    return __int_as_float(__builtin_amdgcn_update_dpp(
        0, __float_as_int(x), 0x130, 0xF, 0xF, true));
}

// Fast reciprocal: single v_rcp_f32 (~1 ulp), no IEEE div sequence.
__device__ __forceinline__ float fast_rcp(float x) {
    return __builtin_amdgcn_rcpf(x);
}

// ---------------- kernel 1: per-plane-segment min/max partials ----------------
__global__ __launch_bounds__(256) void minmax_part(const float* __restrict__ pred,
                                                   const float* __restrict__ targ,
                                                   float* __restrict__ pmx,
                                                   float* __restrict__ pmn) {
    int bx = blockIdx.x;
    int plane = bx >> 4, seg = bx & 15;
    size_t base = (size_t)plane * PLANE + (size_t)seg * 16384;
    const float4* p4 = reinterpret_cast<const float4*>(pred + base);
    const float4* t4 = reinterpret_cast<const float4*>(targ + base);
    float mx = -3.0e38f, mn = 3.0e38f;
    #pragma unroll 4
    for (int i = threadIdx.x; i < 4096; i += 256) {
        float4 a = p4[i], b = t4[i];
        mx = fmaxf(mx, fmaxf(fmaxf(fmaxf(a.x, b.x), fmaxf(a.y, b.y)),
                             fmaxf(fmaxf(a.z, b.z), fmaxf(a.w, b.w))));
        mn = fminf(mn, fminf(fminf(fminf(a.x, b.x), fminf(a.y, b.y)),
                             fminf(fminf(a.z, b.z), fminf(a.w, b.w))));
    }
    #pragma unroll
    for (int off = 32; off; off >>= 1) {
        mx = fmaxf(mx, __shfl_down(mx, off));
        mn = fminf(mn, __shfl_down(mn, off));
    }
    __shared__ float smx[4], smn[4];
    int wid = threadIdx.x >> 6, lane = threadIdx.x & 63;
    if (lane == 0) { smx[wid] = mx; smn[wid] = mn; }
    __syncthreads();
    if (threadIdx.x == 0) {
        pmx[bx] = fmaxf(fmaxf(smx[0], smx[1]), fmaxf(smx[2], smx[3]));
        pmn[bx] = fminf(fminf(smn[0], smn[1]), fminf(smn[2], smn[3]));
    }
}

// ---------------- kernel 2: fused separable SSIM (R12 structure + fast rcp) ---
// 768 blocks x 128 thr = 2 waves/block; wave owns 32 rows, lane owns 8 cols.
// Branch-free clamped loads; 4 running sums {P,T,QQ=PP+TT,PT} packed v2f;
// horizontal 11-tap via prefix + DPP wave shifts; 1/121 folded into c1/c2/EPS;
// SSIM divide via v_rcp_f32 + mul (the IEEE f32 div sequence is ~10 instr with
// a long serial chain — 8/row was the hidden instruction/stall cost).
__global__ __launch_bounds__(128) void ssim_main(const float* __restrict__ pred,
                                                 const float* __restrict__ targ,
                                                 const float* __restrict__ pmx,
                                                 const float* __restrict__ pmn,
                                                 float* __restrict__ parts) {
    __shared__ float red[2];
    int bx = blockIdx.x;
    int plane = bx >> 3, tile = bx & 7;
    int wid = threadIdx.x >> 6, c = threadIdx.x & 63;

    // inline c1/c2 from partials (wave-uniform scalar work)
    float mx = -3.0e38f, mn = 3.0e38f;
    #pragma unroll
    for (int s = 0; s < 16; ++s) {
        mx = fmaxf(mx, pmx[plane * 16 + s]);
        mn = fminf(mn, pmn[plane * 16 + s]);
    }
    float dr = fmaxf(mx - mn, 1e-6f);
    const float c1 = 1.4641f * dr * dr;     // (0.01 dr)^2 * 121^2
    const float c2 = 13.1769f * dr * dr;    // (0.03 dr)^2 * 121^2
    const v2f c1v = {c1, c1}, c2v = {c2, c2};
    const v2f k121 = {121.0f, 121.0f};

    const float* Pg = pred + (size_t)plane * PLANE;
    const float* Tg = targ + (size_t)plane * PLANE;
    int r0 = tile * 64 + wid * 32;

    v2f vsP[4], vsT[4], vsQQ[4], vsPT[4];
    #pragma unroll
    for (int j = 0; j < 4; ++j) { vsP[j] = 0; vsT[j] = 0; vsQQ[j] = 0; vsPT[j] = 0; }

    struct RowData { float4 a0, a1, b0, b1; };

    auto load_row = [&](int r) -> RowData {
        int rc = min(max(r, 0), 511);
        const float4* prow = reinterpret_cast<const float4*>(Pg + (size_t)rc * Wd);
        const float4* trow = reinterpret_cast<const float4*>(Tg + (size_t)rc * Wd);
        RowData d;
        d.a0 = prow[2 * c]; d.a1 = prow[2 * c + 1];
        d.b0 = trow[2 * c]; d.b1 = trow[2 * c + 1];
        return d;
    };

    auto acc_w = [&](const RowData& d, float w) {
        v2f wv = {w, w};
        v2f pa[4] = {{d.a0.x, d.a0.y}, {d.a0.z, d.a0.w}, {d.a1.x, d.a1.y}, {d.a1.z, d.a1.w}};
        v2f tb[4] = {{d.b0.x, d.b0.y}, {d.b0.z, d.b0.w}, {d.b1.x, d.b1.y}, {d.b1.z, d.b1.w}};
        #pragma unroll
        for (int j = 0; j < 4; ++j) {
            vsP[j] += wv * pa[j];
            vsT[j] += wv * tb[j];
            v2f q = pa[j] * pa[j] + tb[j] * tb[j];
            vsQQ[j] += wv * q;
            v2f pt = pa[j] * tb[j];
            vsPT[j] += wv * pt;
        }
    };

    auto hsum = [&](const v2f v[4], v2f H[4]) {
        float P0 = v[0].x;
        float P1 = P0 + v[0].y;
        float P2 = P1 + v[1].x;
        float P3 = P2 + v[1].y;
        float P4 = P3 + v[2].x;
        float P5 = P4 + v[2].y;
        float P6 = P5 + v[3].x;
        float T  = P6 + v[3].y;
        float Tm  = dpp_up1(T);
        float Pm2 = dpp_up1(P2);
        float Pm3 = dpp_up1(P3);
        float Pm4 = dpp_up1(P4);
        float Pm5 = dpp_up1(P5);
        float Pm6 = dpp_up1(P6);
        float Pp0 = dpp_down1(P0);
        float Pp1 = dpp_down1(P1);
        float Pp2 = dpp_down1(P2);
        float Pp3 = dpp_down1(P3);
        float Pp4 = dpp_down1(P4);
        H[0].x = (Tm - Pm2) + P5;
        H[0].y = (Tm - Pm3) + P6;
        H[1].x = (Tm - Pm4) + T;
        H[1].y = (Tm - Pm5) + (T + Pp0);
        H[2].x = (Tm - Pm6) + (T + Pp1);
        H[2].y = T + Pp2;
        H[3].x = (T - P0) + Pp3;
        H[3].y = (T - P1) + Pp4;
    };

    v2f lsum2 = {0.0f, 0.0f};

    auto valid = [&](int r) -> float { return ((unsigned)r < 512u) ? 1.0f : 0.0f; };

    auto body = [&](int it, const RowData& E, const RowData& Lv, RowData& En, RowData& Ln) {
        En = load_row(r0 + it + 6);
        Ln = load_row(r0 + it - 4);

        acc_w(E, valid(r0 + it + 5));

        v2f H[4][4];
        hsum(vsP,  H[0]);
        hsum(vsT,  H[1]);
        hsum(vsQQ, H[2]);
        hsum(vsPT, H[3]);

        #pragma unroll
        for (int j = 0; j < 4; ++j) {
            v2f A = H[0][j], B = H[1][j];
            v2f AB = A * B, A2 = A * A, B2 = B * B;
            v2f t4 = k121 * H[3][j] - AB;
            v2f num = (2.0f * AB + c1v) * (2.0f * t4 + c2v);
            v2f ss = k121 * H[2][j] - A2 - B2;
            ss.x = fmaxf(ss.x, 0.0f); ss.y = fmaxf(ss.y, 0.0f);
            v2f den = (A2 + B2 + c1v) * (ss + c2v);
            float s0 = num.x * fast_rcp(den.x + 214.358881f);  // EPS * 121^4
            float s1 = num.y * fast_rcp(den.y + 214.358881f);
            v2f loss = {fmaxf((1.0f - s0) * 0.5f, 0.0f),
                        fmaxf((1.0f - s1) * 0.5f, 0.0f)};
            lsum2 += loss;
        }
        acc_w(Lv, -valid(r0 + it - 5));
    };

    // init vertical window rows r0-5 .. r0+4, two 5-row bursts (weighted)
    {
        RowData D0 = load_row(r0 - 5), D1 = load_row(r0 - 4), D2 = load_row(r0 - 3),
                D3 = load_row(r0 - 2), D4 = load_row(r0 - 1);
        acc_w(D0, valid(r0 - 5)); acc_w(D1, valid(r0 - 4)); acc_w(D2, valid(r0 - 3));
        acc_w(D3, valid(r0 - 2)); acc_w(D4, valid(r0 - 1));
        RowData D5 = load_row(r0 + 0), D6 = load_row(r0 + 1), D7 = load_row(r0 + 2),
                D8 = load_row(r0 + 3), D9 = load_row(r0 + 4);
        acc_w(D5, 1.0f); acc_w(D6, 1.0f); acc_w(D7, 1.0f);
        acc_w(D8, 1.0f); acc_w(D9, 1.0f);
    }

    RowData E0 = load_row(r0 + 5);
    RowData L0 = load_row(r0 - 5);
    RowData E1, L1;

    #pragma unroll 1
    for (int it = 0; it < 32; it += 2) {
        body(it,     E0, L0, E1, L1);
        body(it + 1, E1, L1, E0, L0);
    }

    float lsum = lsum2.x + lsum2.y;
    #pragma unroll
    for (int off = 32; off; off >>= 1) lsum += __shfl_down(lsum, off);
    if (c == 0) red[wid] = lsum;
    __syncthreads();
    if (threadIdx.x == 0) parts[bx] = red[0] + red[1];
}

// ---------------- kernel 3: deterministic final reduce ----------------
__global__ void finish(const float* __restrict__ parts, float* __restrict__ out,
                       int n, float invN) {
    float s = 0.0f;
    for (int i = threadIdx.x; i < n; i += 256) s += parts[i];
    #pragma unroll
    for (int off = 32; off; off >>= 1) s += __shfl_down(s, off);
    __shared__ float sw[4];
    int wid = threadIdx.x >> 6, lane = threadIdx.x & 63;
    if (lane == 0) sw[wid] = s;
    __syncthreads();
    if (threadIdx.x == 0) out[0] = ((sw[0] + sw[1]) + (sw[2] + sw[3])) * invN;
}

extern "C" void kernel_launch(void* const* d_in, const int* in_sizes, int n_in,
                              void* d_out, int out_size, void* d_ws, size_t ws_size,
                              hipStream_t stream) {
    const float* pred = (const float*)d_in[0];
    const float* targ = (const float*)d_in[1];
    float* out = (float*)d_out;
    int planes = in_sizes[0] / PLANE;  // 96
    int Gm = planes * 16;              // 1536 blocks for minmax
    int Gs = planes * 8;               // 768 blocks for ssim

    float* ws   = (float*)d_ws;
    float* pmx  = ws;                  // Gm
    float* pmn  = ws + Gm;             // Gm
    float* prts = ws + 2 * Gm;         // Gs

    minmax_part<<<Gm, 256, 0, stream>>>(pred, targ, pmx, pmn);
    ssim_main<<<Gs, 128, 0, stream>>>(pred, targ, pmx, pmn, prts);
    float invN = 1.0f / ((float)planes * (float)PLANE);
    finish<<<1, 256, 0, stream>>>(prts, out, Gs, invN);
}